// Round 1
// baseline (156.045 us; speedup 1.0000x reference)
//
#include <hip/hip_runtime.h>
#include <cstdint>
#include <cstddef>

#define S_LEN 2048
#define DMODEL 1024
#define NHEADS 16
#define DKH 64
#define MROWS 4096
#define BH_CNT 32

typedef __bf16 bf16x8 __attribute__((ext_vector_type(8)));
typedef float f32x4 __attribute__((ext_vector_type(4)));
typedef unsigned int u32;
typedef unsigned short u16;

__device__ __forceinline__ u16 f2bfu(float f) {
  u32 u = __float_as_uint(f);
  return (u16)((u + 0x7FFFu + ((u >> 16) & 1u)) >> 16);
}

__device__ __forceinline__ void gload16(void* lds, const void* g) {
  __builtin_amdgcn_global_load_lds(
      (const __attribute__((address_space(1))) void*)g,
      (__attribute__((address_space(3))) void*)lds, 16, 0, 0);
}

// ---------------- prep: x -> bf16 ----------------
__global__ __launch_bounds__(256) void prep_xb_k(const float* __restrict__ x,
                                                 u16* __restrict__ xb) {
  int i = (blockIdx.x * 256 + threadIdx.x) * 4;
  float4 v = *(const float4*)(x + i);
  u32 lo = f2bfu(v.x) | ((u32)f2bfu(v.y) << 16);
  u32 hi = f2bfu(v.z) | ((u32)f2bfu(v.w) << 16);
  *(uint2*)(xb + i) = make_uint2(lo, hi);
}

// ---------------- prep: W^T (n-major) bf16, K pre-scaled ----------------
__global__ __launch_bounds__(256) void prep_w_k(const float* __restrict__ Wq,
    const float* __restrict__ Wk, const float* __restrict__ Wv,
    const float* __restrict__ ps, u16* __restrict__ Wb) {
  __shared__ float tile[32][33];
  int sel = blockIdx.z;
  const float* W = sel == 0 ? Wq : (sel == 1 ? Wk : Wv);
  int k0 = blockIdx.x * 32, c0 = blockIdx.y * 32;
  int tx = threadIdx.x, ty = threadIdx.y;
#pragma unroll
  for (int i = 0; i < 4; ++i)
    tile[ty + i * 8][tx] = W[(size_t)(k0 + ty + i * 8) * DMODEL + c0 + tx];
  __syncthreads();
#pragma unroll
  for (int i = 0; i < 4; ++i) {
    int row = ty + i * 8;
    float v = tile[tx][row];
    if (sel == 1) v *= 0.125f * ps[(c0 + row) >> 6];  // fold 1/sqrt(dk)*phase into K
    Wb[(size_t)(sel * 1024 + c0 + row) * DMODEL + k0 + tx] = f2bfu(v);
  }
}

// ---------------- prep: Wo_eff[d][j] = sum_m (sum_h ent[h][m]) * Wo[m*64+d][j] ----------------
__global__ __launch_bounds__(256) void prep_woeff_k(const float* __restrict__ Wo,
    const float* __restrict__ ent, float* __restrict__ Woeff) {
  __shared__ float e[16];
  int t = threadIdx.x;
  if (t < 16) {
    float s = 0.f;
#pragma unroll
    for (int h = 0; h < 16; ++h) s += ent[h * 16 + t];
    e[t] = s;
  }
  __syncthreads();
  int gid = blockIdx.x * 256 + t;
  int d = gid >> 10, j = gid & 1023;
  float acc = 0.f;
#pragma unroll
  for (int m = 0; m < 16; ++m) acc += e[m] * Wo[(size_t)((m << 6) + d) * DMODEL + j];
  Woeff[(size_t)d * DMODEL + j] = acc;
}

// ---------------- QKV projection GEMM: [4096,1024] x [1024,3072] ----------------
// 128x128 tile, BK=32, 4 waves (2x2), 16x16x32 bf16 MFMA, global_load_lds staging.
__global__ __launch_bounds__(256) void gemm_qkv_k(const u16* __restrict__ xb,
    const u16* __restrict__ Wb, u16* __restrict__ Qb, u16* __restrict__ Kb,
    u16* __restrict__ Vt) {
  __shared__ __align__(16) u16 As[128 * 32];
  __shared__ __align__(16) u16 Bs[128 * 32];
  int tid = threadIdx.x;
  int lane = tid & 63, w = tid >> 6;
  int c = lane & 15, g = lane >> 4;
  int wr = w >> 1, wc = w & 1;
  int m0 = blockIdx.x * 128, n0 = blockIdx.y * 128;
  f32x4 acc[4][4];
#pragma unroll
  for (int i = 0; i < 4; ++i)
#pragma unroll
    for (int j = 0; j < 4; ++j) acc[i][j] = (f32x4){0.f, 0.f, 0.f, 0.f};

  for (int kt = 0; kt < DMODEL; kt += 32) {
    __syncthreads();
#pragma unroll
    for (int j = 0; j < 2; ++j) {
      int cij = (w * 2 + j) * 64 + lane;
      int row = cij >> 2, cc = cij & 3, kp = cc ^ (row & 3);  // swizzled source chunk
      gload16(As + (w * 2 + j) * 512, xb + (size_t)(m0 + row) * DMODEL + kt + kp * 8);
      gload16(Bs + (w * 2 + j) * 512, Wb + (size_t)(n0 + row) * DMODEL + kt + kp * 8);
    }
    __syncthreads();
    bf16x8 af[4], bf[4];
#pragma unroll
    for (int i = 0; i < 4; ++i) {
      int ra = wr * 64 + i * 16 + c;
      af[i] = *(const bf16x8*)(As + ra * 32 + ((g ^ (ra & 3)) * 8));
      int rb = wc * 64 + i * 16 + c;
      bf[i] = *(const bf16x8*)(Bs + rb * 32 + ((g ^ (rb & 3)) * 8));
    }
#pragma unroll
    for (int i = 0; i < 4; ++i)
#pragma unroll
      for (int j = 0; j < 4; ++j)
        acc[i][j] = __builtin_amdgcn_mfma_f32_16x16x32_bf16(af[i], bf[j], acc[i][j], 0, 0, 0);
  }
  int sel = n0 >> 10;
  int nb = n0 & 1023;
#pragma unroll
  for (int i = 0; i < 4; ++i) {
    int mbase = m0 + wr * 64 + i * 16 + 4 * g;
    int b = mbase >> 11, sr = mbase & 2047;
#pragma unroll
    for (int jf = 0; jf < 4; ++jf) {
      int ncol = nb + wc * 64 + jf * 16 + c;
      int h = ncol >> 6, d = ncol & 63;
      int bh = b * 16 + h;
      if (sel == 2) {  // V stored transposed [bh][d][s]
        u32 lo = f2bfu(acc[i][jf][0]) | ((u32)f2bfu(acc[i][jf][1]) << 16);
        u32 hi = f2bfu(acc[i][jf][2]) | ((u32)f2bfu(acc[i][jf][3]) << 16);
        *(uint2*)(Vt + ((size_t)bh * DKH + d) * S_LEN + sr) = make_uint2(lo, hi);
      } else {
        u16* dst = (sel == 0 ? Qb : Kb);
#pragma unroll
        for (int j = 0; j < 4; ++j)
          dst[((size_t)bh * S_LEN + sr + j) * DKH + d] = f2bfu(acc[i][jf][j]);
      }
    }
  }
}

// ---------------- fused cos-softmax flash attention ----------------
// Per block: one (bh, 64-q-rows) tile; 4 waves x 16 q-rows. KBLK=64.
// S^T = mfma(K, Q) so no max needed (w bounded); P restaged via per-wave
// swizzled LDS tile; PV = mfma(V^T, P) accumulating att^T.
__global__ __launch_bounds__(256) void attn_k(const u16* __restrict__ Qb,
    const u16* __restrict__ Kb, const u16* __restrict__ Vt,
    float* __restrict__ attbuf) {
  __shared__ __align__(16) u16 Ks[64 * 64];
  __shared__ __align__(16) u16 Vs[64 * 64];
  __shared__ __align__(16) u32 Ps[4 * 16 * 32];
  int bh = blockIdx.y;
  int tid = threadIdx.x;
  int lane = tid & 63, w = tid >> 6;
  int c = lane & 15, g = lane >> 4;
  int q0 = blockIdx.x * 64 + w * 16;
  const u16* Kbase = Kb + (size_t)bh * S_LEN * DKH;
  const u16* Vbase = Vt + (size_t)bh * DKH * S_LEN;
  bf16x8 qf0, qf1;
  {
    const u16* qp = Qb + ((size_t)bh * S_LEN + q0 + c) * DKH + g * 8;
    qf0 = *(const bf16x8*)qp;
    qf1 = *(const bf16x8*)(qp + 32);
  }
  f32x4 attT[4];
#pragma unroll
  for (int i = 0; i < 4; ++i) attT[i] = (f32x4){0.f, 0.f, 0.f, 0.f};
  float dacc = 0.f;
  u32* Pw = Ps + w * 512;

  for (int kt = 0; kt < S_LEN; kt += 64) {
    __syncthreads();
#pragma unroll
    for (int j = 0; j < 2; ++j) {
      int cij = (w * 2 + j) * 64 + lane;
      int row = cij >> 3, c8 = cij & 7, kp = c8 ^ (row & 7);  // pre-swizzled source
      gload16(Ks + (w * 2 + j) * 512, Kbase + (size_t)(kt + row) * DKH + kp * 8);
      gload16(Vs + (w * 2 + j) * 512, Vbase + (size_t)row * S_LEN + kt + kp * 8);
    }
    __syncthreads();
    f32x4 sT[4];
#pragma unroll
    for (int fm = 0; fm < 4; ++fm) {
      int row = fm * 16 + c;
      bf16x8 a0 = *(const bf16x8*)(Ks + row * 64 + ((g ^ (row & 7)) * 8));
      bf16x8 a1 = *(const bf16x8*)(Ks + row * 64 + (((4 + g) ^ (row & 7)) * 8));
      f32x4 z = (f32x4){0.f, 0.f, 0.f, 0.f};
      z = __builtin_amdgcn_mfma_f32_16x16x32_bf16(a0, qf0, z, 0, 0, 0);
      z = __builtin_amdgcn_mfma_f32_16x16x32_bf16(a1, qf1, z, 0, 0, 0);
      sT[fm] = z;
    }
#pragma unroll
    for (int fm = 0; fm < 4; ++fm) {
      float p[4];
#pragma unroll
      for (int j = 0; j < 4; ++j) {
        float sv = sT[fm][j];                       // already scaled (folded into K)
        float cv = __cosf(sv);
        float wv = __fmaf_rn(0.2f * cv, cv, cv) - 0.1f;  // cos(s)+0.1cos(2s)
        float pv = __expf(wv);                      // no max subtraction needed
        p[j] = pv;
        dacc += pv;
      }
      int kr0 = fm * 16 + 4 * g;
      int ch = (kr0 >> 3) ^ (c & 7);
      int wa = c * 32 + ch * 4 + ((kr0 & 7) >> 1);
      u32 w01 = f2bfu(p[0]) | ((u32)f2bfu(p[1]) << 16);
      u32 w23 = f2bfu(p[2]) | ((u32)f2bfu(p[3]) << 16);
      *(uint2*)(Pw + wa) = make_uint2(w01, w23);
    }
#pragma unroll
    for (int bb = 0; bb < 2; ++bb) {
      bf16x8 pf = *(const bf16x8*)(Pw + c * 32 + (((4 * bb + g) ^ (c & 7)) * 4));
#pragma unroll
      for (int fd = 0; fd < 4; ++fd) {
        int row = fd * 16 + c;
        bf16x8 vf = *(const bf16x8*)(Vs + row * 64 + ((((4 * bb + g) ^ (row & 7))) * 8));
        attT[fd] = __builtin_amdgcn_mfma_f32_16x16x32_bf16(vf, pf, attT[fd], 0, 0, 0);
      }
    }
  }
  dacc += __shfl_xor(dacc, 16, 64);
  dacc += __shfl_xor(dacc, 32, 64);
  float inv = 1.f / dacc;
  float* ob = attbuf + ((size_t)bh * S_LEN + q0 + c) * DKH;
#pragma unroll
  for (int fd = 0; fd < 4; ++fd)
#pragma unroll
    for (int j = 0; j < 4; ++j)
      ob[fd * 16 + 4 * g + j] = attT[fd][j] * inv;
}

// ---------------- head-reduce + a@Wo_eff + bias + residual ----------------
__global__ __launch_bounds__(256) void fuse_out_k(const float* __restrict__ attbuf,
    const float* __restrict__ Woeff, const float* __restrict__ bo,
    const float* __restrict__ x, float* __restrict__ rbuf) {
  __shared__ __align__(16) float a[8][64];
  __shared__ float red[256];
  int t = threadIdx.x;
  int r0 = blockIdx.x * 8;
  int d = t & 63, hg = t >> 6;
  for (int rr = 0; rr < 8; ++rr) {
    int m = r0 + rr, b = m >> 11, sr = m & 2047;
    float pa = 0.f;
#pragma unroll
    for (int hh = 0; hh < 4; ++hh) {
      int h = hg * 4 + hh;
      pa += attbuf[(((size_t)(b * 16 + h)) * S_LEN + sr) * DKH + d];
    }
    red[t] = pa;
    __syncthreads();
    if (hg == 0) a[rr][d] = red[d] + red[64 + d] + red[128 + d] + red[192 + d];
    __syncthreads();
  }
  float o[8][4];
#pragma unroll
  for (int rr = 0; rr < 8; ++rr) { o[rr][0] = o[rr][1] = o[rr][2] = o[rr][3] = 0.f; }
  int c4 = t * 4;
  for (int dd = 0; dd < 64; dd += 4) {
    float4 wv0 = *(const float4*)(Woeff + (size_t)(dd + 0) * DMODEL + c4);
    float4 wv1 = *(const float4*)(Woeff + (size_t)(dd + 1) * DMODEL + c4);
    float4 wv2 = *(const float4*)(Woeff + (size_t)(dd + 2) * DMODEL + c4);
    float4 wv3 = *(const float4*)(Woeff + (size_t)(dd + 3) * DMODEL + c4);
#pragma unroll
    for (int rr = 0; rr < 8; ++rr) {
      float4 av = *(const float4*)&a[rr][dd];
      o[rr][0] += av.x * wv0.x + av.y * wv1.x + av.z * wv2.x + av.w * wv3.x;
      o[rr][1] += av.x * wv0.y + av.y * wv1.y + av.z * wv2.y + av.w * wv3.y;
      o[rr][2] += av.x * wv0.z + av.y * wv1.z + av.z * wv2.z + av.w * wv3.z;
      o[rr][3] += av.x * wv0.w + av.y * wv1.w + av.z * wv2.w + av.w * wv3.w;
    }
  }
  float4 bv = *(const float4*)(bo + c4);
#pragma unroll
  for (int rr = 0; rr < 8; ++rr) {
    int m = r0 + rr;
    float4 xv = *(const float4*)(x + (size_t)m * DMODEL + c4);
    float4 ov;
    ov.x = o[rr][0] + bv.x + xv.x;
    ov.y = o[rr][1] + bv.y + xv.y;
    ov.z = o[rr][2] + bv.z + xv.z;
    ov.w = o[rr][3] + bv.w + xv.w;
    *(float4*)(rbuf + (size_t)m * DMODEL + c4) = ov;
  }
}

// ---------------- LayerNorm ----------------
__global__ __launch_bounds__(256) void ln_k(const float* __restrict__ rbuf,
    const float* __restrict__ gamma, const float* __restrict__ beta,
    float* __restrict__ out) {
  int row = blockIdx.x, t = threadIdx.x;
  int c4 = t * 4;
  float4 rv = *(const float4*)(rbuf + (size_t)row * DMODEL + c4);
  float sum = rv.x + rv.y + rv.z + rv.w;
  float sq = rv.x * rv.x + rv.y * rv.y + rv.z * rv.z + rv.w * rv.w;
#pragma unroll
  for (int m = 1; m < 64; m <<= 1) {
    sum += __shfl_xor(sum, m, 64);
    sq += __shfl_xor(sq, m, 64);
  }
  __shared__ float sred[8];
  int w = t >> 6, lane = t & 63;
  if (lane == 0) { sred[w] = sum; sred[4 + w] = sq; }
  __syncthreads();
  sum = sred[0] + sred[1] + sred[2] + sred[3];
  sq = sred[4] + sred[5] + sred[6] + sred[7];
  float mu = sum * (1.f / 1024.f);
  float var = sq * (1.f / 1024.f) - mu * mu;
  float rs = rsqrtf(var + 1e-6f);
  float4 gv = *(const float4*)(gamma + c4);
  float4 bv = *(const float4*)(beta + c4);
  float4 ov;
  ov.x = gv.x * (rv.x - mu) * rs + bv.x;
  ov.y = gv.y * (rv.y - mu) * rs + bv.y;
  ov.z = gv.z * (rv.z - mu) * rs + bv.z;
  ov.w = gv.w * (rv.w - mu) * rs + bv.w;
  *(float4*)(out + (size_t)row * DMODEL + c4) = ov;
}

extern "C" void kernel_launch(void* const* d_in, const int* in_sizes, int n_in,
                              void* d_out, int out_size, void* d_ws, size_t ws_size,
                              hipStream_t stream) {
  const float* x = (const float*)d_in[0];
  const float* Wq = (const float*)d_in[1];
  const float* Wk = (const float*)d_in[2];
  const float* Wv = (const float*)d_in[3];
  const float* Wo = (const float*)d_in[4];
  const float* bo = (const float*)d_in[5];
  const float* ps = (const float*)d_in[6];
  const float* ent = (const float*)d_in[7];
  const float* gamma = (const float*)d_in[8];
  const float* beta = (const float*)d_in[9];
  float* out = (float*)d_out;

  char* ws = (char*)d_ws;
  size_t o = 0;
  u16* xb = (u16*)(ws + o);    o += (size_t)MROWS * DMODEL * 2;        // 8 MB
  u16* Wb = (u16*)(ws + o);    o += (size_t)3072 * 1024 * 2;           // 6 MB
  u16* Qb = (u16*)(ws + o);    o += (size_t)BH_CNT * S_LEN * DKH * 2;  // 8 MB
  u16* Kb = (u16*)(ws + o);    o += (size_t)BH_CNT * S_LEN * DKH * 2;  // 8 MB
  u16* Vt = (u16*)(ws + o);    o += (size_t)BH_CNT * S_LEN * DKH * 2;  // 8 MB
  float* Woeff = (float*)(ws + o);  o += (size_t)DKH * DMODEL * 4;     // 256 KB
  float* attbuf = (float*)(ws + o); o += (size_t)BH_CNT * S_LEN * DKH * 4;  // 16 MB
  float* rbuf = (float*)(ws + o);   o += (size_t)MROWS * DMODEL * 4;   // 16 MB

  prep_xb_k<<<dim3(4096), dim3(256), 0, stream>>>(x, xb);
  prep_w_k<<<dim3(32, 32, 3), dim3(32, 8), 0, stream>>>(Wq, Wk, Wv, ps, Wb);
  prep_woeff_k<<<dim3(256), dim3(256), 0, stream>>>(Wo, ent, Woeff);
  gemm_qkv_k<<<dim3(32, 24), dim3(256), 0, stream>>>(xb, Wb, Qb, Kb, Vt);
  attn_k<<<dim3(32, 32), dim3(256), 0, stream>>>(Qb, Kb, Vt, attbuf);
  fuse_out_k<<<dim3(512), dim3(256), 0, stream>>>(attbuf, Woeff, bo, x, rbuf);
  ln_k<<<dim3(4096), dim3(256), 0, stream>>>(rbuf, gamma, beta, out);
}

// Round 3
// 141.277 us; speedup vs baseline: 1.1045x; 1.1045x over previous
//
#include <hip/hip_runtime.h>
#include <cstdint>
#include <cstddef>

#define S_LEN 2048
#define DMODEL 1024
#define NHEADS 16
#define DKH 64
#define MROWS 4096
#define BH_CNT 32

typedef __bf16 bf16x8 __attribute__((ext_vector_type(8)));
typedef __bf16 bf16x2 __attribute__((ext_vector_type(2)));
typedef float f32x4 __attribute__((ext_vector_type(4)));
typedef unsigned int u32;
typedef unsigned short u16;

__device__ __forceinline__ u16 f2bfu(float f) {
  u32 u = __float_as_uint(f);
  return (u16)((u + 0x7FFFu + ((u >> 16) & 1u)) >> 16);
}

// compiler-cast bf16 pack (lowers to v_cvt_pk_bf16_f32 on gfx950)
__device__ __forceinline__ u32 pk_bf16(float a, float b) {
  bf16x2 v;
  v[0] = (__bf16)a;
  v[1] = (__bf16)b;
  return __builtin_bit_cast(u32, v);
}

__device__ __forceinline__ void gload16(void* lds, const void* g) {
  __builtin_amdgcn_global_load_lds(
      (const __attribute__((address_space(1))) void*)g,
      (__attribute__((address_space(3))) void*)lds, 16, 0, 0);
}

// ---------------- prep: x -> bf16 ----------------
__global__ __launch_bounds__(256) void prep_xb_k(const float* __restrict__ x,
                                                 u16* __restrict__ xb) {
  int i = (blockIdx.x * 256 + threadIdx.x) * 4;
  float4 v = *(const float4*)(x + i);
  *(uint2*)(xb + i) = make_uint2(pk_bf16(v.x, v.y), pk_bf16(v.z, v.w));
}

// ---------------- prep: W^T (n-major) bf16, K pre-scaled ----------------
__global__ __launch_bounds__(256) void prep_w_k(const float* __restrict__ Wq,
    const float* __restrict__ Wk, const float* __restrict__ Wv,
    const float* __restrict__ ps, u16* __restrict__ Wb) {
  __shared__ float tile[32][33];
  int sel = blockIdx.z;
  const float* W = sel == 0 ? Wq : (sel == 1 ? Wk : Wv);
  int k0 = blockIdx.x * 32, c0 = blockIdx.y * 32;
  int tx = threadIdx.x, ty = threadIdx.y;
#pragma unroll
  for (int i = 0; i < 4; ++i)
    tile[ty + i * 8][tx] = W[(size_t)(k0 + ty + i * 8) * DMODEL + c0 + tx];
  __syncthreads();
#pragma unroll
  for (int i = 0; i < 4; ++i) {
    int row = ty + i * 8;
    float v = tile[tx][row];
    if (sel == 1) v *= 0.125f * ps[(c0 + row) >> 6];  // fold 1/sqrt(dk)*phase into K
    Wb[(size_t)(sel * 1024 + c0 + row) * DMODEL + k0 + tx] = f2bfu(v);
  }
}

// ---------------- prep: Wo_eff[d][j] = sum_m (sum_h ent[h][m]) * Wo[m*64+d][j] ----------------
__global__ __launch_bounds__(256) void prep_woeff_k(const float* __restrict__ Wo,
    const float* __restrict__ ent, float* __restrict__ Woeff) {
  __shared__ float e[16];
  int t = threadIdx.x;
  if (t < 16) {
    float s = 0.f;
#pragma unroll
    for (int h = 0; h < 16; ++h) s += ent[h * 16 + t];
    e[t] = s;
  }
  __syncthreads();
  int gid = blockIdx.x * 256 + t;
  int d = gid >> 10, j = gid & 1023;
  float acc = 0.f;
#pragma unroll
  for (int m = 0; m < 16; ++m) acc += e[m] * Wo[(size_t)((m << 6) + d) * DMODEL + j];
  Woeff[(size_t)d * DMODEL + j] = acc;
}

// ---------------- QKV projection GEMM: [4096,1024] x [1024,3072] ----------------
// 128x128 tile, BK=32, double-buffered staging, one barrier per K-step.
__global__ __launch_bounds__(256) void gemm_qkv_k(const u16* __restrict__ xb,
    const u16* __restrict__ Wb, u16* __restrict__ Qb, u16* __restrict__ Kb,
    u16* __restrict__ Vt) {
  __shared__ __align__(16) u16 As[2][128 * 32];
  __shared__ __align__(16) u16 Bs[2][128 * 32];
  int tid = threadIdx.x;
  int lane = tid & 63, w = tid >> 6;
  int c = lane & 15, g = lane >> 4;
  int wr = w >> 1, wc = w & 1;
  int m0 = blockIdx.x * 128, n0 = blockIdx.y * 128;

  int cij0 = (w * 2) * 64 + lane, cij1 = (w * 2 + 1) * 64 + lane;
  int row0 = cij0 >> 2, kp0 = (cij0 & 3) ^ (row0 & 3);
  int row1 = cij1 >> 2, kp1 = (cij1 & 3) ^ (row1 & 3);
  const u16* a0p = xb + (size_t)(m0 + row0) * DMODEL + kp0 * 8;
  const u16* a1p = xb + (size_t)(m0 + row1) * DMODEL + kp1 * 8;
  const u16* b0p = Wb + (size_t)(n0 + row0) * DMODEL + kp0 * 8;
  const u16* b1p = Wb + (size_t)(n0 + row1) * DMODEL + kp1 * 8;

  f32x4 acc[4][4];
#pragma unroll
  for (int i = 0; i < 4; ++i)
#pragma unroll
    for (int j = 0; j < 4; ++j) acc[i][j] = (f32x4){0.f, 0.f, 0.f, 0.f};

  // prologue stage
  gload16(&As[0][(w * 2) * 512], a0p);
  gload16(&As[0][(w * 2 + 1) * 512], a1p);
  gload16(&Bs[0][(w * 2) * 512], b0p);
  gload16(&Bs[0][(w * 2 + 1) * 512], b1p);
  __syncthreads();

  int cur = 0;
  for (int kt = 0; kt < DMODEL; kt += 32) {
    if (kt + 32 < DMODEL) {
      int nx = cur ^ 1, ko = kt + 32;
      gload16(&As[nx][(w * 2) * 512], a0p + ko);
      gload16(&As[nx][(w * 2 + 1) * 512], a1p + ko);
      gload16(&Bs[nx][(w * 2) * 512], b0p + ko);
      gload16(&Bs[nx][(w * 2 + 1) * 512], b1p + ko);
    }
    const u16* Ac = As[cur];
    const u16* Bc = Bs[cur];
    bf16x8 af[4], bf[4];
#pragma unroll
    for (int i = 0; i < 4; ++i) {
      int ra = wr * 64 + i * 16 + c;
      af[i] = *(const bf16x8*)(Ac + ra * 32 + ((g ^ (ra & 3)) * 8));
      int rb = wc * 64 + i * 16 + c;
      bf[i] = *(const bf16x8*)(Bc + rb * 32 + ((g ^ (rb & 3)) * 8));
    }
#pragma unroll
    for (int i = 0; i < 4; ++i)
#pragma unroll
      for (int j = 0; j < 4; ++j)
        acc[i][j] = __builtin_amdgcn_mfma_f32_16x16x32_bf16(af[i], bf[j], acc[i][j], 0, 0, 0);
    __syncthreads();
    cur ^= 1;
  }

  int sel = n0 >> 10;
  int nb = n0 & 1023;
#pragma unroll
  for (int i = 0; i < 4; ++i) {
    int mbase = m0 + wr * 64 + i * 16 + 4 * g;
    int b = mbase >> 11, sr = mbase & 2047;
#pragma unroll
    for (int jf = 0; jf < 4; ++jf) {
      int ncol = nb + wc * 64 + jf * 16 + c;
      int h = ncol >> 6, d = ncol & 63;
      int bh = b * 16 + h;
      if (sel == 2) {  // V stored transposed [bh][d][s]
        *(uint2*)(Vt + ((size_t)bh * DKH + d) * S_LEN + sr) =
            make_uint2(pk_bf16(acc[i][jf][0], acc[i][jf][1]),
                       pk_bf16(acc[i][jf][2], acc[i][jf][3]));
      } else {
        u16* dst = (sel == 0 ? Qb : Kb);
#pragma unroll
        for (int j = 0; j < 4; ++j) {
          __bf16 hv = (__bf16)acc[i][jf][j];
          dst[((size_t)bh * S_LEN + sr + j) * DKH + d] = __builtin_bit_cast(u16, hv);
        }
      }
    }
  }
}

// ---------------- fused cos-softmax flash attention ----------------
// Per block: one (bh, 64-q-rows) tile; 4 waves x 16 q-rows. KBLK=64.
// Double-buffered K/V staging, one barrier per tile. S^T = mfma(K, Q);
// transform exp(cos s + 0.1 cos 2s) = exp2(fma(cv, fma(.2L, cv, L), -.1L));
// P restaged through per-wave swizzled LDS; PV = mfma(V^T, P).
__global__ __launch_bounds__(256) void attn_k(const u16* __restrict__ Qb,
    const u16* __restrict__ Kb, const u16* __restrict__ Vt,
    float* __restrict__ attbuf) {
  __shared__ __align__(16) u16 Ks[2][64 * 64];
  __shared__ __align__(16) u16 Vs[2][64 * 64];
  __shared__ __align__(16) u32 Ps[4 * 16 * 32];
  int bh = blockIdx.y;
  int tid = threadIdx.x;
  int lane = tid & 63, w = tid >> 6;
  int c = lane & 15, g = lane >> 4;
  int q0 = blockIdx.x * 64 + w * 16;
  const u16* Kbase = Kb + (size_t)bh * S_LEN * DKH;
  const u16* Vbase = Vt + (size_t)bh * DKH * S_LEN;

  int cij0 = (w * 2) * 64 + lane, cij1 = (w * 2 + 1) * 64 + lane;
  int srow0 = cij0 >> 3, skp0 = (cij0 & 7) ^ (srow0 & 7);
  int srow1 = cij1 >> 3, skp1 = (cij1 & 7) ^ (srow1 & 7);
  const u16* k0p = Kbase + (size_t)srow0 * DKH + skp0 * 8;
  const u16* k1p = Kbase + (size_t)srow1 * DKH + skp1 * 8;
  const u16* v0p = Vbase + (size_t)srow0 * S_LEN + skp0 * 8;
  const u16* v1p = Vbase + (size_t)srow1 * S_LEN + skp1 * 8;

  // prologue stage tile 0
  gload16(&Ks[0][(w * 2) * 512], k0p);
  gload16(&Ks[0][(w * 2 + 1) * 512], k1p);
  gload16(&Vs[0][(w * 2) * 512], v0p);
  gload16(&Vs[0][(w * 2 + 1) * 512], v1p);

  bf16x8 qf0, qf1;
  {
    const u16* qp = Qb + ((size_t)bh * S_LEN + q0 + c) * DKH + g * 8;
    qf0 = *(const bf16x8*)qp;
    qf1 = *(const bf16x8*)(qp + 32);
  }
  f32x4 attT[4];
#pragma unroll
  for (int i = 0; i < 4; ++i) attT[i] = (f32x4){0.f, 0.f, 0.f, 0.f};
  float dacc0 = 0.f, dacc1 = 0.f;
  u32* Pw = Ps + w * 512;
  int wAddr[4];
#pragma unroll
  for (int fm = 0; fm < 4; ++fm) {
    int kr0 = fm * 16 + 4 * g;
    int ch = (kr0 >> 3) ^ (c & 7);
    wAddr[fm] = c * 32 + ch * 4 + ((kr0 & 7) >> 1);
  }
  const float L2E = 1.4426950408889634f;

  __syncthreads();
  int cur = 0;
  for (int kt = 0; kt < S_LEN; kt += 64) {
    if (kt + 64 < S_LEN) {
      int nx = cur ^ 1, ko = kt + 64;
      gload16(&Ks[nx][(w * 2) * 512], k0p + (size_t)ko * DKH);
      gload16(&Ks[nx][(w * 2 + 1) * 512], k1p + (size_t)ko * DKH);
      gload16(&Vs[nx][(w * 2) * 512], v0p + ko);
      gload16(&Vs[nx][(w * 2 + 1) * 512], v1p + ko);
    }
    const u16* Kc = Ks[cur];
    const u16* Vc = Vs[cur];
    f32x4 sT[4];
#pragma unroll
    for (int fm = 0; fm < 4; ++fm) {
      int row = fm * 16 + c;
      bf16x8 a0 = *(const bf16x8*)(Kc + row * 64 + ((g ^ (row & 7)) * 8));
      bf16x8 a1 = *(const bf16x8*)(Kc + row * 64 + (((4 + g) ^ (row & 7)) * 8));
      f32x4 z = (f32x4){0.f, 0.f, 0.f, 0.f};
      z = __builtin_amdgcn_mfma_f32_16x16x32_bf16(a0, qf0, z, 0, 0, 0);
      z = __builtin_amdgcn_mfma_f32_16x16x32_bf16(a1, qf1, z, 0, 0, 0);
      sT[fm] = z;
    }
#pragma unroll
    for (int fm = 0; fm < 4; ++fm) {
      float pv[4];
#pragma unroll
      for (int j = 0; j < 4; ++j) {
        float cv = __cosf(sT[fm][j]);  // v_mul + v_cos (scale folded into K)
        float w2 = __fmaf_rn(cv, __fmaf_rn(0.2f * L2E, cv, L2E), -0.1f * L2E);
        pv[j] = __builtin_amdgcn_exp2f(w2);  // single v_exp_f32
      }
      dacc0 += pv[0] + pv[1];
      dacc1 += pv[2] + pv[3];
      *(uint2*)(Pw + wAddr[fm]) = make_uint2(pk_bf16(pv[0], pv[1]), pk_bf16(pv[2], pv[3]));
    }
#pragma unroll
    for (int bb = 0; bb < 2; ++bb) {
      bf16x8 pf = *(const bf16x8*)(Pw + c * 32 + (((4 * bb + g) ^ (c & 7)) * 4));
#pragma unroll
      for (int fd = 0; fd < 4; ++fd) {
        int row = fd * 16 + c;
        bf16x8 vf = *(const bf16x8*)(Vc + row * 64 + ((((4 * bb + g) ^ (row & 7))) * 8));
        attT[fd] = __builtin_amdgcn_mfma_f32_16x16x32_bf16(vf, pf, attT[fd], 0, 0, 0);
      }
    }
    __syncthreads();
    cur ^= 1;
  }
  float dacc = dacc0 + dacc1;
  dacc += __shfl_xor(dacc, 16, 64);
  dacc += __shfl_xor(dacc, 32, 64);
  float inv = 1.f / dacc;
  float* ob = attbuf + ((size_t)bh * S_LEN + q0 + c) * DKH;
#pragma unroll
  for (int fd = 0; fd < 4; ++fd)
#pragma unroll
    for (int j = 0; j < 4; ++j)
      ob[fd * 16 + 4 * g + j] = attT[fd][j] * inv;
}

// ---------------- head-reduce + a@Wo_eff + bias + residual + LayerNorm ----------------
__global__ __launch_bounds__(256) void fuse_out_ln_k(const float* __restrict__ attbuf,
    const float* __restrict__ Woeff, const float* __restrict__ bo,
    const float* __restrict__ x, const float* __restrict__ gamma,
    const float* __restrict__ beta, float* __restrict__ out) {
  __shared__ float red[8][256];
  __shared__ __align__(16) float a[8][64];
  __shared__ float sred[8][4][2];
  int t = threadIdx.x;
  int r0 = blockIdx.x * 8;
  int d = t & 63, hg = t >> 6;
#pragma unroll
  for (int rr = 0; rr < 8; ++rr) {
    int m = r0 + rr, b = m >> 11, sr = m & 2047;
    float pa = 0.f;
#pragma unroll
    for (int hh = 0; hh < 4; ++hh) {
      int h = hg * 4 + hh;
      pa += attbuf[(((size_t)(b * 16 + h)) * S_LEN + sr) * DKH + d];
    }
    red[rr][t] = pa;
  }
  __syncthreads();
#pragma unroll
  for (int e = 0; e < 2; ++e) {
    int idx = t + e * 256;
    int rr = idx >> 6, dd = idx & 63;
    a[rr][dd] = red[rr][dd] + red[rr][64 + dd] + red[rr][128 + dd] + red[rr][192 + dd];
  }
  __syncthreads();

  float o[8][4];
#pragma unroll
  for (int rr = 0; rr < 8; ++rr) { o[rr][0] = o[rr][1] = o[rr][2] = o[rr][3] = 0.f; }
  int c4 = t * 4;
  for (int dd = 0; dd < 64; dd += 4) {
    float4 wv0 = *(const float4*)(Woeff + (size_t)(dd + 0) * DMODEL + c4);
    float4 wv1 = *(const float4*)(Woeff + (size_t)(dd + 1) * DMODEL + c4);
    float4 wv2 = *(const float4*)(Woeff + (size_t)(dd + 2) * DMODEL + c4);
    float4 wv3 = *(const float4*)(Woeff + (size_t)(dd + 3) * DMODEL + c4);
#pragma unroll
    for (int rr = 0; rr < 8; ++rr) {
      float4 av = *(const float4*)&a[rr][dd];
      o[rr][0] += av.x * wv0.x + av.y * wv1.x + av.z * wv2.x + av.w * wv3.x;
      o[rr][1] += av.x * wv0.y + av.y * wv1.y + av.z * wv2.y + av.w * wv3.y;
      o[rr][2] += av.x * wv0.z + av.y * wv1.z + av.z * wv2.z + av.w * wv3.z;
      o[rr][3] += av.x * wv0.w + av.y * wv1.w + av.z * wv2.w + av.w * wv3.w;
    }
  }
  float4 bv = *(const float4*)(bo + c4);
  int w = t >> 6, lane = t & 63;
#pragma unroll
  for (int rr = 0; rr < 8; ++rr) {
    int m = r0 + rr;
    float4 xv = *(const float4*)(x + (size_t)m * DMODEL + c4);
    o[rr][0] += bv.x + xv.x;
    o[rr][1] += bv.y + xv.y;
    o[rr][2] += bv.z + xv.z;
    o[rr][3] += bv.w + xv.w;
    float s = o[rr][0] + o[rr][1] + o[rr][2] + o[rr][3];
    float q = o[rr][0] * o[rr][0] + o[rr][1] * o[rr][1] + o[rr][2] * o[rr][2] + o[rr][3] * o[rr][3];
#pragma unroll
    for (int mm = 1; mm < 64; mm <<= 1) {
      s += __shfl_xor(s, mm, 64);
      q += __shfl_xor(q, mm, 64);
    }
    if (lane == 0) { sred[rr][w][0] = s; sred[rr][w][1] = q; }
  }
  __syncthreads();
  float4 gv = *(const float4*)(gamma + c4);
  float4 bev = *(const float4*)(beta + c4);
#pragma unroll
  for (int rr = 0; rr < 8; ++rr) {
    float s = sred[rr][0][0] + sred[rr][1][0] + sred[rr][2][0] + sred[rr][3][0];
    float q = sred[rr][0][1] + sred[rr][1][1] + sred[rr][2][1] + sred[rr][3][1];
    float mu = s * (1.f / 1024.f);
    float var = q * (1.f / 1024.f) - mu * mu;
    float rs = rsqrtf(var + 1e-6f);
    int m = r0 + rr;
    float4 ov;
    ov.x = gv.x * (o[rr][0] - mu) * rs + bev.x;
    ov.y = gv.y * (o[rr][1] - mu) * rs + bev.y;
    ov.z = gv.z * (o[rr][2] - mu) * rs + bev.z;
    ov.w = gv.w * (o[rr][3] - mu) * rs + bev.w;
    *(float4*)(out + (size_t)m * DMODEL + c4) = ov;
  }
}

extern "C" void kernel_launch(void* const* d_in, const int* in_sizes, int n_in,
                              void* d_out, int out_size, void* d_ws, size_t ws_size,
                              hipStream_t stream) {
  const float* x = (const float*)d_in[0];
  const float* Wq = (const float*)d_in[1];
  const float* Wk = (const float*)d_in[2];
  const float* Wv = (const float*)d_in[3];
  const float* Wo = (const float*)d_in[4];
  const float* bo = (const float*)d_in[5];
  const float* ps = (const float*)d_in[6];
  const float* ent = (const float*)d_in[7];
  const float* gamma = (const float*)d_in[8];
  const float* beta = (const float*)d_in[9];
  float* out = (float*)d_out;

  char* ws = (char*)d_ws;
  size_t o = 0;
  u16* xb = (u16*)(ws + o);    o += (size_t)MROWS * DMODEL * 2;        // 8 MB
  u16* Wb = (u16*)(ws + o);    o += (size_t)3072 * 1024 * 2;           // 6 MB
  u16* Qb = (u16*)(ws + o);    o += (size_t)BH_CNT * S_LEN * DKH * 2;  // 8 MB
  u16* Kb = (u16*)(ws + o);    o += (size_t)BH_CNT * S_LEN * DKH * 2;  // 8 MB
  u16* Vt = (u16*)(ws + o);    o += (size_t)BH_CNT * S_LEN * DKH * 2;  // 8 MB
  float* Woeff = (float*)(ws + o);  o += (size_t)DKH * DMODEL * 4;     // 256 KB
  float* attbuf = (float*)(ws + o); o += (size_t)BH_CNT * S_LEN * DKH * 4;  // 16 MB

  prep_xb_k<<<dim3(4096), dim3(256), 0, stream>>>(x, xb);
  prep_w_k<<<dim3(32, 32, 3), dim3(32, 8), 0, stream>>>(Wq, Wk, Wv, ps, Wb);
  prep_woeff_k<<<dim3(256), dim3(256), 0, stream>>>(Wo, ent, Woeff);
  gemm_qkv_k<<<dim3(32, 24), dim3(256), 0, stream>>>(xb, Wb, Qb, Kb, Vt);
  attn_k<<<dim3(32, 32), dim3(256), 0, stream>>>(Qb, Kb, Vt, attbuf);
  fuse_out_ln_k<<<dim3(512), dim3(256), 0, stream>>>(attbuf, Woeff, bo, x, gamma, beta, out);
}

// Round 4
// 139.107 us; speedup vs baseline: 1.1218x; 1.0156x over previous
//
#include <hip/hip_runtime.h>
#include <cstdint>
#include <cstddef>

#define S_LEN 2048
#define DMODEL 1024
#define NHEADS 16
#define DKH 64
#define MROWS 4096
#define BH_CNT 32

typedef __bf16 bf16x8 __attribute__((ext_vector_type(8)));
typedef __bf16 bf16x2 __attribute__((ext_vector_type(2)));
typedef float f32x4 __attribute__((ext_vector_type(4)));
typedef unsigned int u32;
typedef unsigned short u16;

__device__ __forceinline__ u16 f2bfu(float f) {
  u32 u = __float_as_uint(f);
  return (u16)((u + 0x7FFFu + ((u >> 16) & 1u)) >> 16);
}

// compiler-cast bf16 pack (lowers to v_cvt_pk_bf16_f32 on gfx950)
__device__ __forceinline__ u32 pk_bf16(float a, float b) {
  bf16x2 v;
  v[0] = (__bf16)a;
  v[1] = (__bf16)b;
  return __builtin_bit_cast(u32, v);
}

__device__ __forceinline__ void gload16(void* lds, const void* g) {
  __builtin_amdgcn_global_load_lds(
      (const __attribute__((address_space(1))) void*)g,
      (__attribute__((address_space(3))) void*)lds, 16, 0, 0);
}

// ---------------- prep: x -> bf16 ----------------
__global__ __launch_bounds__(256) void prep_xb_k(const float* __restrict__ x,
                                                 u16* __restrict__ xb) {
  int i = (blockIdx.x * 256 + threadIdx.x) * 4;
  float4 v = *(const float4*)(x + i);
  *(uint2*)(xb + i) = make_uint2(pk_bf16(v.x, v.y), pk_bf16(v.z, v.w));
}

// ---------------- prep: W^T (n-major) bf16, K pre-scaled ----------------
// K scale folds 1/sqrt(dk)*phase AND 1/(2pi): scores arrive in REVOLUTIONS,
// so attention uses raw v_cos (no range-reduce mul).
__global__ __launch_bounds__(256) void prep_w_k(const float* __restrict__ Wq,
    const float* __restrict__ Wk, const float* __restrict__ Wv,
    const float* __restrict__ ps, u16* __restrict__ Wb) {
  __shared__ float tile[32][33];
  int sel = blockIdx.z;
  const float* W = sel == 0 ? Wq : (sel == 1 ? Wk : Wv);
  int k0 = blockIdx.x * 32, c0 = blockIdx.y * 32;
  int tx = threadIdx.x, ty = threadIdx.y;
#pragma unroll
  for (int i = 0; i < 4; ++i)
    tile[ty + i * 8][tx] = W[(size_t)(k0 + ty + i * 8) * DMODEL + c0 + tx];
  __syncthreads();
#pragma unroll
  for (int i = 0; i < 4; ++i) {
    int row = ty + i * 8;
    float v = tile[tx][row];
    if (sel == 1) v *= 0.019894367886486918f * ps[(c0 + row) >> 6];  // 0.125/(2pi)
    Wb[(size_t)(sel * 1024 + c0 + row) * DMODEL + k0 + tx] = f2bfu(v);
  }
}

// ---------------- prep: Wo_eff[d][j] = sum_m (sum_h ent[h][m]) * Wo[m*64+d][j] ----------------
__global__ __launch_bounds__(256) void prep_woeff_k(const float* __restrict__ Wo,
    const float* __restrict__ ent, float* __restrict__ Woeff) {
  __shared__ float e[16];
  int t = threadIdx.x;
  if (t < 16) {
    float s = 0.f;
#pragma unroll
    for (int h = 0; h < 16; ++h) s += ent[h * 16 + t];
    e[t] = s;
  }
  __syncthreads();
  int gid = blockIdx.x * 256 + t;
  int d = gid >> 10, j = gid & 1023;
  float acc = 0.f;
#pragma unroll
  for (int m = 0; m < 16; ++m) acc += e[m] * Wo[(size_t)((m << 6) + d) * DMODEL + j];
  Woeff[(size_t)d * DMODEL + j] = acc;
}

// ---------------- QKV projection GEMM: [4096,1024] x [1024,3072] ----------------
// 128x128 tile, BK=32, double-buffered staging, one barrier per K-step.
// Epilogue: C-tile staged through LDS (XOR-swizzled) -> fully coalesced
// 128B-run global stores (incl. the V transpose).
__global__ __launch_bounds__(256) void gemm_qkv_k(const u16* __restrict__ xb,
    const u16* __restrict__ Wb, u16* __restrict__ Qb, u16* __restrict__ Kb,
    u16* __restrict__ Vt) {
  __shared__ __align__(16) u16 SMEM[2][2][128 * 32];  // [A/B][dbuf][tile]
  int tid = threadIdx.x;
  int lane = tid & 63, w = tid >> 6;
  int c = lane & 15, g = lane >> 4;
  int wr = w >> 1, wc = w & 1;
  int m0 = blockIdx.x * 128, n0 = blockIdx.y * 128;

  int cij0 = (w * 2) * 64 + lane, cij1 = (w * 2 + 1) * 64 + lane;
  int row0 = cij0 >> 2, kp0 = (cij0 & 3) ^ (row0 & 3);
  int row1 = cij1 >> 2, kp1 = (cij1 & 3) ^ (row1 & 3);
  const u16* a0p = xb + (size_t)(m0 + row0) * DMODEL + kp0 * 8;
  const u16* a1p = xb + (size_t)(m0 + row1) * DMODEL + kp1 * 8;
  const u16* b0p = Wb + (size_t)(n0 + row0) * DMODEL + kp0 * 8;
  const u16* b1p = Wb + (size_t)(n0 + row1) * DMODEL + kp1 * 8;

  f32x4 acc[4][4];
#pragma unroll
  for (int i = 0; i < 4; ++i)
#pragma unroll
    for (int j = 0; j < 4; ++j) acc[i][j] = (f32x4){0.f, 0.f, 0.f, 0.f};

  // prologue stage
  gload16(&SMEM[0][0][(w * 2) * 512], a0p);
  gload16(&SMEM[0][0][(w * 2 + 1) * 512], a1p);
  gload16(&SMEM[1][0][(w * 2) * 512], b0p);
  gload16(&SMEM[1][0][(w * 2 + 1) * 512], b1p);
  __syncthreads();

  int cur = 0;
  for (int kt = 0; kt < DMODEL; kt += 32) {
    if (kt + 32 < DMODEL) {
      int nx = cur ^ 1, ko = kt + 32;
      gload16(&SMEM[0][nx][(w * 2) * 512], a0p + ko);
      gload16(&SMEM[0][nx][(w * 2 + 1) * 512], a1p + ko);
      gload16(&SMEM[1][nx][(w * 2) * 512], b0p + ko);
      gload16(&SMEM[1][nx][(w * 2 + 1) * 512], b1p + ko);
    }
    const u16* Ac = SMEM[0][cur];
    const u16* Bc = SMEM[1][cur];
    bf16x8 af[4], bf[4];
#pragma unroll
    for (int i = 0; i < 4; ++i) {
      int ra = wr * 64 + i * 16 + c;
      af[i] = *(const bf16x8*)(Ac + ra * 32 + ((g ^ (ra & 3)) * 8));
      int rb = wc * 64 + i * 16 + c;
      bf[i] = *(const bf16x8*)(Bc + rb * 32 + ((g ^ (rb & 3)) * 8));
    }
#pragma unroll
    for (int i = 0; i < 4; ++i)
#pragma unroll
      for (int j = 0; j < 4; ++j)
        acc[i][j] = __builtin_amdgcn_mfma_f32_16x16x32_bf16(af[i], bf[j], acc[i][j], 0, 0, 0);
    __syncthreads();
    cur ^= 1;
  }

  // ---- epilogue via LDS (reuse staging buffers: 32KB = 128x128 u16) ----
  int sel = n0 >> 10;
  char* Ls = (char*)&SMEM[0][0][0];
  if (sel == 2) {
    // LDS layout transposed: row = n-local (d), col = m-local (s)
#pragma unroll
    for (int i = 0; i < 4; ++i)
#pragma unroll
      for (int jf = 0; jf < 4; ++jf) {
        int n = wc * 64 + jf * 16 + c;
        int m = wr * 64 + i * 16 + 4 * g;
        int byte = n * 256 + ((m * 2) ^ ((n & 7) << 4));
        *(uint2*)(Ls + byte) = make_uint2(pk_bf16(acc[i][jf][0], acc[i][jf][1]),
                                          pk_bf16(acc[i][jf][2], acc[i][jf][3]));
      }
  } else {
    // LDS layout: row = m-local (s), col = n-local (d)
#pragma unroll
    for (int i = 0; i < 4; ++i)
#pragma unroll
      for (int jf = 0; jf < 4; ++jf) {
        int n = wc * 64 + jf * 16 + c;
#pragma unroll
        for (int j = 0; j < 4; ++j) {
          int m = wr * 64 + i * 16 + 4 * g + j;
          int byte = m * 256 + ((n * 2) ^ ((m & 7) << 4));
          __bf16 hv = (__bf16)acc[i][jf][j];
          *(u16*)(Ls + byte) = __builtin_bit_cast(u16, hv);
        }
      }
  }
  __syncthreads();
  int r = tid >> 1, half = tid & 1;
  int h0 = (n0 & 1023) >> 6;
  int b = m0 >> 11, sbase = m0 & 2047;
  u16* dst;
  if (sel == 2) {
    int bh = b * 16 + h0 + (r >> 6), d = r & 63;
    dst = Vt + ((size_t)bh * DKH + d) * S_LEN + sbase + half * 64;
  } else {
    u16* base = (sel == 0 ? Qb : Kb);
    int bh = b * 16 + h0 + half;
    dst = base + ((size_t)bh * S_LEN + sbase + r) * DKH;
  }
#pragma unroll
  for (int kk = 0; kk < 8; ++kk) {
    int byte = r * 256 + ((half * 128 + kk * 16) ^ ((r & 7) << 4));
    *(uint4*)(dst + kk * 8) = *(const uint4*)(Ls + byte);
  }
}

// ---------------- fused cos-softmax flash attention ----------------
// 1-D grid with XCD swizzle (heads cluster per-XCD so K/V stay L2-resident).
// Per block: one (bh, 64-q-rows) tile; 4 waves x 16 q-rows. KBLK=64,
// double-buffered, manually 2x-unrolled for static LDS indexing.
// Scores arrive in revolutions (scale folded into K) -> raw v_cos.
__global__ __launch_bounds__(256) void attn_k(const u16* __restrict__ Qb,
    const u16* __restrict__ Kb, const u16* __restrict__ Vt,
    float* __restrict__ attbuf) {
  __shared__ __align__(16) u16 Ks[2][64 * 64];
  __shared__ __align__(16) u16 Vs[2][64 * 64];
  __shared__ __align__(16) u32 Ps[4 * 16 * 32];
  int fid = blockIdx.x;
  int swz = (fid & 7) * 128 + (fid >> 3);  // 1024 blocks, 8 XCDs -> bijective
  int bh = swz >> 5, qblk = swz & 31;
  int tid = threadIdx.x;
  int lane = tid & 63, w = tid >> 6;
  int c = lane & 15, g = lane >> 4;
  int q0 = qblk * 64 + w * 16;
  const u16* Kbase = Kb + (size_t)bh * S_LEN * DKH;
  const u16* Vbase = Vt + (size_t)bh * DKH * S_LEN;

  int cij0 = (w * 2) * 64 + lane, cij1 = (w * 2 + 1) * 64 + lane;
  int srow0 = cij0 >> 3, skp0 = (cij0 & 7) ^ (srow0 & 7);
  int srow1 = cij1 >> 3, skp1 = (cij1 & 7) ^ (srow1 & 7);
  const u16* k0p = Kbase + (size_t)srow0 * DKH + skp0 * 8;
  const u16* k1p = Kbase + (size_t)srow1 * DKH + skp1 * 8;
  const u16* v0p = Vbase + (size_t)srow0 * S_LEN + skp0 * 8;
  const u16* v1p = Vbase + (size_t)srow1 * S_LEN + skp1 * 8;

  // prologue stage tile 0 into buf 0
  gload16(&Ks[0][(w * 2) * 512], k0p);
  gload16(&Ks[0][(w * 2 + 1) * 512], k1p);
  gload16(&Vs[0][(w * 2) * 512], v0p);
  gload16(&Vs[0][(w * 2 + 1) * 512], v1p);

  bf16x8 qf0, qf1;
  {
    const u16* qp = Qb + ((size_t)bh * S_LEN + q0 + c) * DKH + g * 8;
    qf0 = *(const bf16x8*)qp;
    qf1 = *(const bf16x8*)(qp + 32);
  }
  f32x4 attT[4];
#pragma unroll
  for (int i = 0; i < 4; ++i) attT[i] = (f32x4){0.f, 0.f, 0.f, 0.f};
  float dacc0 = 0.f, dacc1 = 0.f;
  u32* Pw = Ps + w * 512;
  int wAddr[4];
#pragma unroll
  for (int fm = 0; fm < 4; ++fm) {
    int kr0 = fm * 16 + 4 * g;
    int ch = (kr0 >> 3) ^ (c & 7);
    wAddr[fm] = c * 32 + ch * 4 + ((kr0 & 7) >> 1);
  }
  const float L2E = 1.4426950408889634f;

  auto compute = [&](const u16* Kc, const u16* Vc) {
    f32x4 sT[4];
    __builtin_amdgcn_s_setprio(1);
#pragma unroll
    for (int fm = 0; fm < 4; ++fm) {
      int row = fm * 16 + c;
      bf16x8 a0 = *(const bf16x8*)(Kc + row * 64 + ((g ^ (row & 7)) * 8));
      bf16x8 a1 = *(const bf16x8*)(Kc + row * 64 + (((4 + g) ^ (row & 7)) * 8));
      f32x4 z = (f32x4){0.f, 0.f, 0.f, 0.f};
      z = __builtin_amdgcn_mfma_f32_16x16x32_bf16(a0, qf0, z, 0, 0, 0);
      z = __builtin_amdgcn_mfma_f32_16x16x32_bf16(a1, qf1, z, 0, 0, 0);
      sT[fm] = z;
    }
    __builtin_amdgcn_s_setprio(0);
#pragma unroll
    for (int fm = 0; fm < 4; ++fm) {
      float pv[4];
#pragma unroll
      for (int j = 0; j < 4; ++j) {
        float cv = __builtin_amdgcn_cosf(sT[fm][j]);  // input in revolutions
        float w2 = __fmaf_rn(cv, __fmaf_rn(0.2f * L2E, cv, L2E), -0.1f * L2E);
        pv[j] = __builtin_amdgcn_exp2f(w2);
      }
      dacc0 += pv[0] + pv[1];
      dacc1 += pv[2] + pv[3];
      *(uint2*)(Pw + wAddr[fm]) = make_uint2(pk_bf16(pv[0], pv[1]), pk_bf16(pv[2], pv[3]));
    }
    __builtin_amdgcn_s_setprio(1);
#pragma unroll
    for (int bb = 0; bb < 2; ++bb) {
      bf16x8 pf = *(const bf16x8*)(Pw + c * 32 + (((4 * bb + g) ^ (c & 7)) * 4));
#pragma unroll
      for (int fd = 0; fd < 4; ++fd) {
        int row = fd * 16 + c;
        bf16x8 vf = *(const bf16x8*)(Vc + row * 64 + ((((4 * bb + g) ^ (row & 7))) * 8));
        attT[fd] = __builtin_amdgcn_mfma_f32_16x16x32_bf16(vf, pf, attT[fd], 0, 0, 0);
      }
    }
    __builtin_amdgcn_s_setprio(0);
  };

  const u16* kc0 = k0p;
  const u16* kc1 = k1p;
  const u16* vc0 = v0p;
  const u16* vc1 = v1p;
  __syncthreads();
  for (int kt = 0; kt < S_LEN; kt += 128) {
    // stage tile (kt+64) into buf1
    kc0 += 64 * DKH; kc1 += 64 * DKH; vc0 += 64; vc1 += 64;
    gload16(&Ks[1][(w * 2) * 512], kc0);
    gload16(&Ks[1][(w * 2 + 1) * 512], kc1);
    gload16(&Vs[1][(w * 2) * 512], vc0);
    gload16(&Vs[1][(w * 2 + 1) * 512], vc1);
    compute(Ks[0], Vs[0]);
    __syncthreads();
    if (kt + 128 < S_LEN) {  // stage tile (kt+128) into buf0
      kc0 += 64 * DKH; kc1 += 64 * DKH; vc0 += 64; vc1 += 64;
      gload16(&Ks[0][(w * 2) * 512], kc0);
      gload16(&Ks[0][(w * 2 + 1) * 512], kc1);
      gload16(&Vs[0][(w * 2) * 512], vc0);
      gload16(&Vs[0][(w * 2 + 1) * 512], vc1);
    }
    compute(Ks[1], Vs[1]);
    __syncthreads();
  }
  float dacc = dacc0 + dacc1;
  dacc += __shfl_xor(dacc, 16, 64);
  dacc += __shfl_xor(dacc, 32, 64);
  float inv = 1.f / dacc;
  float* ob = attbuf + ((size_t)bh * S_LEN + q0 + c) * DKH;
#pragma unroll
  for (int fd = 0; fd < 4; ++fd) {
    float4 ov;
    ov.x = attT[fd][0] * inv;
    ov.y = attT[fd][1] * inv;
    ov.z = attT[fd][2] * inv;
    ov.w = attT[fd][3] * inv;
    *(float4*)(ob + fd * 16 + 4 * g) = ov;
  }
}

// ---------------- head-reduce + a@Wo_eff + bias + residual + LayerNorm ----------------
__global__ __launch_bounds__(256) void fuse_out_ln_k(const float* __restrict__ attbuf,
    const float* __restrict__ Woeff, const float* __restrict__ bo,
    const float* __restrict__ x, const float* __restrict__ gamma,
    const float* __restrict__ beta, float* __restrict__ out) {
  __shared__ float red[8][256];
  __shared__ __align__(16) float a[8][64];
  __shared__ float sred[8][4][2];
  int t = threadIdx.x;
  int r0 = blockIdx.x * 8;
  int d = t & 63, hg = t >> 6;
#pragma unroll
  for (int rr = 0; rr < 8; ++rr) {
    int m = r0 + rr, b = m >> 11, sr = m & 2047;
    float pa = 0.f;
#pragma unroll
    for (int hh = 0; hh < 4; ++hh) {
      int h = hg * 4 + hh;
      pa += attbuf[(((size_t)(b * 16 + h)) * S_LEN + sr) * DKH + d];
    }
    red[rr][t] = pa;
  }
  __syncthreads();
#pragma unroll
  for (int e = 0; e < 2; ++e) {
    int idx = t + e * 256;
    int rr = idx >> 6, dd = idx & 63;
    a[rr][dd] = red[rr][dd] + red[rr][64 + dd] + red[rr][128 + dd] + red[rr][192 + dd];
  }
  __syncthreads();

  float o[8][4];
#pragma unroll
  for (int rr = 0; rr < 8; ++rr) { o[rr][0] = o[rr][1] = o[rr][2] = o[rr][3] = 0.f; }
  int c4 = t * 4;
  for (int dd = 0; dd < 64; dd += 4) {
    float4 wv0 = *(const float4*)(Woeff + (size_t)(dd + 0) * DMODEL + c4);
    float4 wv1 = *(const float4*)(Woeff + (size_t)(dd + 1) * DMODEL + c4);
    float4 wv2 = *(const float4*)(Woeff + (size_t)(dd + 2) * DMODEL + c4);
    float4 wv3 = *(const float4*)(Woeff + (size_t)(dd + 3) * DMODEL + c4);
#pragma unroll
    for (int rr = 0; rr < 8; ++rr) {
      float4 av = *(const float4*)&a[rr][dd];
      o[rr][0] += av.x * wv0.x + av.y * wv1.x + av.z * wv2.x + av.w * wv3.x;
      o[rr][1] += av.x * wv0.y + av.y * wv1.y + av.z * wv2.y + av.w * wv3.y;
      o[rr][2] += av.x * wv0.z + av.y * wv1.z + av.z * wv2.z + av.w * wv3.z;
      o[rr][3] += av.x * wv0.w + av.y * wv1.w + av.z * wv2.w + av.w * wv3.w;
    }
  }
  float4 bv = *(const float4*)(bo + c4);
  int w = t >> 6, lane = t & 63;
#pragma unroll
  for (int rr = 0; rr < 8; ++rr) {
    int m = r0 + rr;
    float4 xv = *(const float4*)(x + (size_t)m * DMODEL + c4);
    o[rr][0] += bv.x + xv.x;
    o[rr][1] += bv.y + xv.y;
    o[rr][2] += bv.z + xv.z;
    o[rr][3] += bv.w + xv.w;
    float s = o[rr][0] + o[rr][1] + o[rr][2] + o[rr][3];
    float q = o[rr][0] * o[rr][0] + o[rr][1] * o[rr][1] + o[rr][2] * o[rr][2] + o[rr][3] * o[rr][3];
#pragma unroll
    for (int mm = 1; mm < 64; mm <<= 1) {
      s += __shfl_xor(s, mm, 64);
      q += __shfl_xor(q, mm, 64);
    }
    if (lane == 0) { sred[rr][w][0] = s; sred[rr][w][1] = q; }
  }
  __syncthreads();
  float4 gv = *(const float4*)(gamma + c4);
  float4 bev = *(const float4*)(beta + c4);
#pragma unroll
  for (int rr = 0; rr < 8; ++rr) {
    float s = sred[rr][0][0] + sred[rr][1][0] + sred[rr][2][0] + sred[rr][3][0];
    float q = sred[rr][0][1] + sred[rr][1][1] + sred[rr][2][1] + sred[rr][3][1];
    float mu = s * (1.f / 1024.f);
    float var = q * (1.f / 1024.f) - mu * mu;
    float rs = rsqrtf(var + 1e-6f);
    int m = r0 + rr;
    float4 ov;
    ov.x = gv.x * (o[rr][0] - mu) * rs + bev.x;
    ov.y = gv.y * (o[rr][1] - mu) * rs + bev.y;
    ov.z = gv.z * (o[rr][2] - mu) * rs + bev.z;
    ov.w = gv.w * (o[rr][3] - mu) * rs + bev.w;
    *(float4*)(out + (size_t)m * DMODEL + c4) = ov;
  }
}

extern "C" void kernel_launch(void* const* d_in, const int* in_sizes, int n_in,
                              void* d_out, int out_size, void* d_ws, size_t ws_size,
                              hipStream_t stream) {
  const float* x = (const float*)d_in[0];
  const float* Wq = (const float*)d_in[1];
  const float* Wk = (const float*)d_in[2];
  const float* Wv = (const float*)d_in[3];
  const float* Wo = (const float*)d_in[4];
  const float* bo = (const float*)d_in[5];
  const float* ps = (const float*)d_in[6];
  const float* ent = (const float*)d_in[7];
  const float* gamma = (const float*)d_in[8];
  const float* beta = (const float*)d_in[9];
  float* out = (float*)d_out;

  char* ws = (char*)d_ws;
  size_t o = 0;
  u16* xb = (u16*)(ws + o);    o += (size_t)MROWS * DMODEL * 2;        // 8 MB
  u16* Wb = (u16*)(ws + o);    o += (size_t)3072 * 1024 * 2;           // 6 MB
  u16* Qb = (u16*)(ws + o);    o += (size_t)BH_CNT * S_LEN * DKH * 2;  // 8 MB
  u16* Kb = (u16*)(ws + o);    o += (size_t)BH_CNT * S_LEN * DKH * 2;  // 8 MB
  u16* Vt = (u16*)(ws + o);    o += (size_t)BH_CNT * S_LEN * DKH * 2;  // 8 MB
  float* Woeff = (float*)(ws + o);  o += (size_t)DKH * DMODEL * 4;     // 256 KB
  float* attbuf = (float*)(ws + o); o += (size_t)BH_CNT * S_LEN * DKH * 4;  // 16 MB

  prep_xb_k<<<dim3(4096), dim3(256), 0, stream>>>(x, xb);
  prep_w_k<<<dim3(32, 32, 3), dim3(32, 8), 0, stream>>>(Wq, Wk, Wv, ps, Wb);
  prep_woeff_k<<<dim3(256), dim3(256), 0, stream>>>(Wo, ent, Woeff);
  gemm_qkv_k<<<dim3(32, 24), dim3(256), 0, stream>>>(xb, Wb, Qb, Kb, Vt);
  attn_k<<<dim3(1024), dim3(256), 0, stream>>>(Qb, Kb, Vt, attbuf);
  fuse_out_ln_k<<<dim3(512), dim3(256), 0, stream>>>(attbuf, Woeff, bo, x, gamma, beta, out);
}